// Round 1
// 839.926 us; speedup vs baseline: 1.0153x; 1.0153x over previous
//
#include <hip/hip_runtime.h>

#define C 512
#define HW 4096
#define EPSV 1e-5f

typedef _Float16 fp16x8 __attribute__((ext_vector_type(8)));
typedef _Float16 fp16x4 __attribute__((ext_vector_type(4)));
typedef float f32x4 __attribute__((ext_vector_type(4)));

// ---- workspace layout (bytes) ----
#define OFF_MC    (0)
#define OFF_RC    (8192)
#define OFF_MS    (16384)
#define OFF_RS    (24576)
#define OFF_BETAF (32768)
#define OFF_V     (40960)
#define OFF_BZ    (49152)
#define OFF_T     (65536)                      // t[b][m] f32, 64 KB
#define OFF_SP    (131072)                     // stats partials float2[2][4][512][64] = 2 MB
#define OFF_A     (OFF_SP + 2097152)           // 1 MB
#define OFF_WZ    (OFF_A + 1048576)            // 1 MB
#define OFF_XCT   (OFF_WZ + 1048576)           // 16 MB
#define OFF_XST   (OFF_XCT + 16777216)         // 16 MB
#define OFF_KT    (OFF_XST + 16777216)         // 16 MB
#define OFF_HM    (OFF_KT + 16777216)          // 16 MB
#define OFF_ML    (OFF_HM + 16777216)          // float2[4][4096][64] = 8 MB
#define OFF_S     (OFF_ML + 8388608)           // f16 [4][4096][4096] = 128 MB
// total ~= 204 MB

// ---------------------------------------------------------------------------
// 1) fused transpose + f16 cast + partial stats (single read of fp32 input)
// ---------------------------------------------------------------------------
__global__ void transpose_stats_kernel(const float* __restrict__ xc, const float* __restrict__ xs,
                                       char* __restrict__ ws)
{
    int bx = blockIdx.x;                  // 4096 = 2 * 4 * 8 * 64
    int tensor = bx >> 11, b = (bx >> 9) & 3, c0 = ((bx >> 6) & 7) * 64, n0 = (bx & 63) * 64;
    const float* src = tensor ? xs : xc;
    _Float16* dst = (_Float16*)(ws + (tensor ? OFF_XST : OFF_XCT));
    float2* part = (float2*)(ws + OFF_SP);

    __shared__ _Float16 tile[64][72];
    __shared__ float sred[4][64], ssred[4][64];

    int tid = threadIdx.x, cR = tid & 63, ng = tid >> 6;
    const float* p = src + ((size_t)(b * C + c0 + cR)) * HW + n0 + ng * 16;
    float s = 0.f, ss = 0.f;
    #pragma unroll
    for (int k = 0; k < 4; k++) {
        float4 v = *(const float4*)(p + k * 4);
        s += v.x + v.y + v.z + v.w;
        ss += v.x * v.x + v.y * v.y + v.z * v.z + v.w * v.w;
        int n = ng * 16 + k * 4;
        tile[n][cR] = (_Float16)v.x; tile[n + 1][cR] = (_Float16)v.y;
        tile[n + 2][cR] = (_Float16)v.z; tile[n + 3][cR] = (_Float16)v.w;
    }
    sred[ng][cR] = s; ssred[ng][cR] = ss;
    __syncthreads();
    if (tid < 64) {
        float S = sred[0][tid] + sred[1][tid] + sred[2][tid] + sred[3][tid];
        float SS = ssred[0][tid] + ssred[1][tid] + ssred[2][tid] + ssred[3][tid];
        part[((size_t)((tensor * 4 + b) * 512 + c0 + tid)) * 64 + (n0 >> 6)] = make_float2(S, SS);
    }
    #pragma unroll
    for (int i = 0; i < 2; i++) {
        int g = tid + i * 256, row = g >> 3, c8 = (g & 7) * 8;
        *(fp16x8*)&dst[((size_t)(b * HW + n0 + row)) * C + c0 + c8] = *(const fp16x8*)&tile[row][c8];
    }
}

// ---------------------------------------------------------------------------
// 1b) finalize stats
// ---------------------------------------------------------------------------
__global__ void finalize_stats_kernel(char* __restrict__ ws)
{
    int ch = blockIdx.x * 256 + threadIdx.x;       // 16 blocks -> 4096 channels
    const float2* part = (const float2*)(ws + OFF_SP) + (size_t)ch * 64;
    float S = 0.f, SS = 0.f;
    for (int k = 0; k < 64; k++) { float2 v = part[k]; S += v.x; SS += v.y; }
    int tensor = ch >> 11, rem = ch & 2047;
    float m = S / (float)HW;
    float var = (SS - S * m) / (float)(HW - 1) + EPSV;   // unbiased (n-1) + EPS
    ((float*)(ws + (tensor ? OFF_MS : OFF_MC)))[rem] = m;
    ((float*)(ws + (tensor ? OFF_RS : OFF_RC)))[rem] = rsqrtf(var);
}

// ---------------------------------------------------------------------------
// 2) small precomputes: A = Wf^T Wg, Wz = Wo Wh, betaf, bz = Wo bh
// ---------------------------------------------------------------------------
__global__ void precompute_kernel(const float* __restrict__ Wf, const float* __restrict__ Wg,
                                  const float* __restrict__ Wo, const float* __restrict__ Wh,
                                  const float* __restrict__ bf, const float* __restrict__ bh,
                                  char* __restrict__ ws)
{
    float* A = (float*)(ws + OFF_A);
    float* Wz = (float*)(ws + OFF_WZ);
    float* betaf = (float*)(ws + OFF_BETAF);
    float* bz = (float*)(ws + OFF_BZ);
    const float* mc = (const float*)(ws + OFF_MC);
    const float* rc = (const float*)(ws + OFF_RC);
    int bx = blockIdx.x, t = threadIdx.x;
    if (bx < 512) {                              // A or Wz, 2 output rows per block
        bool isA = bx < 256;
        int r0 = (isA ? bx : bx - 256) * 2;
        float a00 = 0.f, a01 = 0.f, a10 = 0.f, a11 = 0.f;
        for (int k = 0; k < C; k++) {
            float r0v, r1v, c0v, c1v;
            if (isA) {                           // A[i][j] = sum_co Wf[co][i]*Wg[co][j]
                r0v = Wf[k * C + r0]; r1v = Wf[k * C + r0 + 1];
                c0v = Wg[k * C + t];  c1v = Wg[k * C + t + 256];
            } else {                             // Wz[o][j] = sum_i Wo[o][i]*Wh[i][j]
                r0v = Wo[r0 * C + k]; r1v = Wo[(r0 + 1) * C + k];
                c0v = Wh[k * C + t];  c1v = Wh[k * C + t + 256];
            }
            a00 += r0v * c0v; a01 += r0v * c1v;
            a10 += r1v * c0v; a11 += r1v * c1v;
        }
        float* D = isA ? A : Wz;
        D[r0 * C + t] = a00;       D[r0 * C + t + 256] = a01;
        D[(r0 + 1) * C + t] = a10; D[(r0 + 1) * C + t + 256] = a11;
    } else if (bx < 520) {                       // betaf[b][co] = bf[co] - sum_i Wf[co][i]*mc*rc
        int g = (bx - 512) * 256 + t, b = g >> 9, co = g & 511;
        float acc = 0.f;
        for (int i = 0; i < C; i++) acc += Wf[co * C + i] * mc[b * C + i] * rc[b * C + i];
        betaf[g] = bf[co] - acc;
    } else {                                     // bz[co] = sum_i Wo[co][i]*bh[i]
        int co = (bx - 520) * 256 + t;
        float acc = 0.f;
        for (int i = 0; i < C; i++) acc += Wo[co * C + i] * bh[i];
        bz[co] = acc;
    }
}

// v[b][j] = rs[b][j] * sum_co betaf[b][co]*Wg[co][j]
__global__ void precompute_v_kernel(const float* __restrict__ Wg, char* __restrict__ ws)
{
    const float* betaf = (const float*)(ws + OFF_BETAF);
    const float* rs = (const float*)(ws + OFF_RS);
    float* v = (float*)(ws + OFF_V);
    int g = blockIdx.x * 32 + (threadIdx.x >> 3);   // 0..2047 output index
    int b = g >> 9, j = g & 511, cq = threadIdx.x & 7;
    float acc = 0.f;
    for (int co = cq * 64; co < cq * 64 + 64; co++) acc += betaf[b * C + co] * Wg[co * C + j];
    acc += __shfl_xor(acc, 1);
    acc += __shfl_xor(acc, 2);
    acc += __shfl_xor(acc, 4);
    if (cq == 0) v[g] = rs[b * C + j] * acc;
}

// ---------------------------------------------------------------------------
// 3) fused prep GEMM -> Kt (transposed, f16) and Hm (f16)
// ---------------------------------------------------------------------------
__global__ void __launch_bounds__(256) prep_gemm_kernel(char* __restrict__ ws)
{
    const float* A = (const float*)(ws + OFF_A);
    const float* Wz = (const float*)(ws + OFF_WZ);
    const float* rc = (const float*)(ws + OFF_RC);
    const float* rs = (const float*)(ws + OFF_RS);
    const float* bz = (const float*)(ws + OFF_BZ);
    const _Float16* __restrict__ xsT = (const _Float16*)(ws + OFF_XST);
    _Float16* __restrict__ Kt = (_Float16*)(ws + OFF_KT);
    _Float16* __restrict__ Hm = (_Float16*)(ws + OFF_HM);

    int bx = blockIdx.x;                 // 1024 = 4b * 8 rowblk * 32 mblk
    int b = bx & 3, rest = bx >> 2;
    int r128 = rest >> 5, mb = rest & 31;
    int r0 = r128 * 128, m0 = mb * 128;
    int w = threadIdx.x >> 6, lane = threadIdx.x & 63, q = lane >> 4, l16 = lane & 15;
    int wr = (w & 1) * 64, wm = (w >> 1) * 64;
    bool isK = (r0 < 512);
    const float* Asrc = isK ? A : Wz;
    int rbase = (isK ? r0 : r0 - 512) + wr;

    f32x4 zz = {0.f, 0.f, 0.f, 0.f};
    f32x4 acc[4][4];
    #pragma unroll
    for (int rt = 0; rt < 4; rt++)
        #pragma unroll
        for (int mt = 0; mt < 4; mt++) acc[rt][mt] = zz;

    float rcv[4];
    #pragma unroll
    for (int rt = 0; rt < 4; rt++)
        rcv[rt] = isK ? rc[b * C + rbase + rt * 16 + l16] : 1.f;

    for (int ks = 0; ks < 16; ks++) {
        int j0 = ks * 32 + q * 8;
        float rsv[8];
        if (isK) {
            float4 u0 = *(const float4*)&rs[b * C + j0];
            float4 u1 = *(const float4*)&rs[b * C + j0 + 4];
            rsv[0] = u0.x; rsv[1] = u0.y; rsv[2] = u0.z; rsv[3] = u0.w;
            rsv[4] = u1.x; rsv[5] = u1.y; rsv[6] = u1.z; rsv[7] = u1.w;
        } else {
            #pragma unroll
            for (int jj = 0; jj < 8; jj++) rsv[jj] = 1.f;
        }
        fp16x8 afr[4];
        #pragma unroll
        for (int rt = 0; rt < 4; rt++) {
            int row = rbase + rt * 16 + l16;
            float4 a0 = *(const float4*)&Asrc[row * C + j0];
            float4 a1 = *(const float4*)&Asrc[row * C + j0 + 4];
            float av8[8];
            av8[0] = a0.x; av8[1] = a0.y; av8[2] = a0.z; av8[3] = a0.w;
            av8[4] = a1.x; av8[5] = a1.y; av8[6] = a1.z; av8[7] = a1.w;
            float sc = rcv[rt];
            #pragma unroll
            for (int jj = 0; jj < 8; jj++)
                afr[rt][jj] = (_Float16)(isK ? av8[jj] * sc * rsv[jj] : av8[jj]);
        }
        fp16x8 bfr[4];
        #pragma unroll
        for (int mt = 0; mt < 4; mt++)
            bfr[mt] = *(const fp16x8*)&xsT[((size_t)(b * HW + m0 + wm + mt * 16 + l16)) * C + j0];
        #pragma unroll
        for (int rt = 0; rt < 4; rt++)
            #pragma unroll
            for (int mt = 0; mt < 4; mt++)
                acc[rt][mt] = __builtin_amdgcn_mfma_f32_16x16x32_f16(afr[rt], bfr[mt], acc[rt][mt], 0, 0, 0);
    }

    if (isK) {
        #pragma unroll
        for (int rt = 0; rt < 4; rt++)
            #pragma unroll
            for (int mt = 0; mt < 4; mt++) {
                int m = m0 + wm + mt * 16 + l16;
                int cb = r0 + wr + rt * 16 + q * 4;
                fp16x4 h;
                h[0] = (_Float16)acc[rt][mt][0]; h[1] = (_Float16)acc[rt][mt][1];
                h[2] = (_Float16)acc[rt][mt][2]; h[3] = (_Float16)acc[rt][mt][3];
                *(fp16x4*)&Kt[((size_t)(b * HW + m)) * C + cb] = h;
            }
    } else {
        #pragma unroll
        for (int rt = 0; rt < 4; rt++) {
            float bzv[4];
            #pragma unroll
            for (int reg = 0; reg < 4; reg++) bzv[reg] = bz[rbase + rt * 16 + q * 4 + reg];
            #pragma unroll
            for (int mt = 0; mt < 4; mt++) {
                int m = m0 + wm + mt * 16 + l16;
                #pragma unroll
                for (int reg = 0; reg < 4; reg++) {
                    int co = rbase + rt * 16 + q * 4 + reg;
                    Hm[((size_t)(b * C + co)) * HW + m] = (_Float16)(acc[rt][mt][reg] + bzv[reg]);
                }
            }
        }
    }
}

// ---------------------------------------------------------------------------
// 4) t[b][m] = sum_j v[b][j] * xsT[b][m][j]
// ---------------------------------------------------------------------------
__global__ void t_kernel(char* __restrict__ ws)
{
    const float* v = (const float*)(ws + OFF_V);
    const _Float16* __restrict__ xsT = (const _Float16*)(ws + OFF_XST);
    float* tG = (float*)(ws + OFF_T);
    int bx = blockIdx.x;                      // 512 = 4 b * 128 mchunks(32)
    int b = bx >> 7, m0 = (bx & 127) * 32;
    int m = m0 + (threadIdx.x >> 3), cq = threadIdx.x & 7;
    const _Float16* p = xsT + ((size_t)(b * HW + m)) * C + cq * 64;
    const float* vp = v + b * C + cq * 64;
    float acc = 0.f;
    #pragma unroll
    for (int k = 0; k < 8; k++) {
        fp16x8 xv = *(const fp16x8*)(p + k * 8);
        float4 v0 = *(const float4*)(vp + k * 8);
        float4 v1 = *(const float4*)(vp + k * 8 + 4);
        acc += (float)xv[0] * v0.x + (float)xv[1] * v0.y + (float)xv[2] * v0.z + (float)xv[3] * v0.w
             + (float)xv[4] * v1.x + (float)xv[5] * v1.y + (float)xv[6] * v1.z + (float)xv[7] * v1.w;
    }
    acc += __shfl_xor(acc, 1);
    acc += __shfl_xor(acc, 2);
    acc += __shfl_xor(acc, 4);
    if (cq == 0) tG[b * HW + m] = acc;
}

// ---------------------------------------------------------------------------
// 5) pass A: S-tile = Q @ Kt^T (128x128, K=512) + t[m]; per-(row, 64-m-tile)
//    max & sumexp; stores p = exp(s - tilemax) f16 to S, (max,sum) to ML.
// ---------------------------------------------------------------------------
__global__ void __launch_bounds__(256, 4) qk_kernel(char* __restrict__ ws)
{
    const _Float16* __restrict__ xcT = (const _Float16*)(ws + OFF_XCT);
    const _Float16* __restrict__ Kt = (const _Float16*)(ws + OFF_KT);
    const float* __restrict__ tG = (const float*)(ws + OFF_T);
    float2* __restrict__ ML = (float2*)(ws + OFF_ML);
    _Float16* __restrict__ Sg = (_Float16*)(ws + OFF_S);

    int bx = blockIdx.x;                  // 4096: low3 = b*2+mhi (XCD-pinned)
    int b = (bx >> 1) & 3, mhi = bx & 1;
    int rest = bx >> 3, mlo = rest & 15, ntile = rest >> 4;
    int m0 = (mhi * 16 + mlo) * 128, n0 = ntile * 128;
    int tid = threadIdx.x, w = tid >> 6, lane = tid & 63, q = lane >> 4, l16 = lane & 15;
    int wn = (w & 1) * 64, wm = (w >> 1) * 64;

    const _Float16* ab = xcT + ((size_t)(b * HW + n0 + wn + l16)) * C;
    const _Float16* bb = Kt + ((size_t)(b * HW + m0 + wm + l16)) * C;

    f32x4 zz = {0.f, 0.f, 0.f, 0.f};
    f32x4 acc[4][4];
    #pragma unroll
    for (int nt = 0; nt < 4; nt++)
        #pragma unroll
        for (int mt = 0; mt < 4; mt++) acc[nt][mt] = zz;

    #pragma unroll 4
    for (int ks = 0; ks < 16; ks++) {
        int k = ks * 32 + q * 8;
        fp16x8 afr[4], bfr[4];
        #pragma unroll
        for (int nt = 0; nt < 4; nt++) afr[nt] = *(const fp16x8*)(ab + (size_t)nt * 16 * C + k);
        #pragma unroll
        for (int mt = 0; mt < 4; mt++) bfr[mt] = *(const fp16x8*)(bb + (size_t)mt * 16 * C + k);
        #pragma unroll
        for (int nt = 0; nt < 4; nt++)
            #pragma unroll
            for (int mt = 0; mt < 4; mt++)
                acc[nt][mt] = __builtin_amdgcn_mfma_f32_16x16x32_f16(afr[nt], bfr[mt], acc[nt][mt], 0, 0, 0);
    }

    // ---- epilogue: + t[m], per-row tile max / exp / sum ----
    float tv[4];
    #pragma unroll
    for (int mt = 0; mt < 4; mt++) tv[mt] = tG[b * HW + m0 + wm + mt * 16 + l16];
    #pragma unroll
    for (int nt = 0; nt < 4; nt++)
        #pragma unroll
        for (int mt = 0; mt < 4; mt++)
            #pragma unroll
            for (int reg = 0; reg < 4; reg++) acc[nt][mt][reg] += tv[mt];

    float rm[4][4], sum[4][4];
    #pragma unroll
    for (int nt = 0; nt < 4; nt++)
        #pragma unroll
        for (int reg = 0; reg < 4; reg++)
            rm[nt][reg] = fmaxf(fmaxf(acc[nt][0][reg], acc[nt][1][reg]),
                                fmaxf(acc[nt][2][reg], acc[nt][3][reg]));
    #pragma unroll
    for (int s = 1; s < 16; s <<= 1)
        #pragma unroll
        for (int nt = 0; nt < 4; nt++)
            #pragma unroll
            for (int reg = 0; reg < 4; reg++)
                rm[nt][reg] = fmaxf(rm[nt][reg], __shfl_xor(rm[nt][reg], s));
    #pragma unroll
    for (int nt = 0; nt < 4; nt++)
        #pragma unroll
        for (int reg = 0; reg < 4; reg++) sum[nt][reg] = 0.f;
    #pragma unroll
    for (int nt = 0; nt < 4; nt++)
        #pragma unroll
        for (int mt = 0; mt < 4; mt++)
            #pragma unroll
            for (int reg = 0; reg < 4; reg++) {
                float pv = __expf(acc[nt][mt][reg] - rm[nt][reg]);
                acc[nt][mt][reg] = pv;
                sum[nt][reg] += pv;
            }
    #pragma unroll
    for (int s = 1; s < 16; s <<= 1)
        #pragma unroll
        for (int nt = 0; nt < 4; nt++)
            #pragma unroll
            for (int reg = 0; reg < 4; reg++)
                sum[nt][reg] += __shfl_xor(sum[nt][reg], s);

    int tl = (m0 + wm) >> 6;
    if (l16 == 0) {
        #pragma unroll
        for (int nt = 0; nt < 4; nt++)
            #pragma unroll
            for (int reg = 0; reg < 4; reg++)
                ML[((size_t)(b * HW + n0 + wn + nt * 16 + q * 4 + reg)) * 64 + tl] =
                    make_float2(rm[nt][reg], sum[nt][reg]);
    }

    // ---- f16 + LDS transpose-spill, then coalesced 16B stores to S ----
    __shared__ _Float16 Pl[4][64][72];
    #pragma unroll
    for (int nt = 0; nt < 4; nt++)
        #pragma unroll
        for (int mt = 0; mt < 4; mt++)
            #pragma unroll
            for (int reg = 0; reg < 4; reg++)
                Pl[w][nt * 16 + q * 4 + reg][mt * 16 + l16] = (_Float16)acc[nt][mt][reg];
    __syncthreads();
    #pragma unroll
    for (int i = 0; i < 8; i++) {
        int row = i * 8 + (lane >> 3), c8 = (lane & 7) * 8;
        *(fp16x8*)&Sg[((size_t)(b * HW + n0 + wn + row)) * HW + m0 + wm + c8] =
            *(const fp16x8*)&Pl[w][row][c8];
    }
}

// ---------------------------------------------------------------------------
// 6) pass C: O = (p * scale) @ Hm^T ; 64-row n-tiles, 512-thread blocks so
//    FOUR independent blocks co-reside per CU (110 KB LDS, 2048 thr) and
//    hide each other's barrier + L2-latency stalls. S read once per
//    (n-tile, cohalf); LDS double-buffered 64-key chunks; reduce_ml folded
//    into the prologue. XCD-pinned: bx&7 = cohalf*4 + b.
// ---------------------------------------------------------------------------
__global__ void __launch_bounds__(512, 4) pv_kernel(const float* __restrict__ xc,
                                                    const float* __restrict__ bo,
                                                    float* __restrict__ out,
                                                    char* __restrict__ ws)
{
    const _Float16* __restrict__ Sg = (const _Float16*)(ws + OFF_S);
    const _Float16* __restrict__ Hm = (const _Float16*)(ws + OFF_HM);
    const float2* __restrict__ ML = (const float2*)(ws + OFF_ML);

    int bx = blockIdx.x;                  // 512 = 64 ntile * (cohalf*4 + b)
    int b = bx & 3, cohalf = (bx >> 2) & 1, ntile = bx >> 3;
    int n0 = ntile * 64, co0 = cohalf * 256;
    int tid = threadIdx.x, w = tid >> 6, lane = tid & 63, q = lane >> 4, l16 = lane & 15;
    int wn = (w & 1) * 32, wc = (w >> 1) * 64;

    __shared__ _Float16 SclH[64][72];         // [tile][row], f16 scales
    __shared__ _Float16 Al[2][64][72];        // S chunk, 64 keys, padded

    // ---- prologue: per-row global softmax scale (was reduce_ml) ----
    {
        int row = tid >> 3, g = tid & 7;          // 64 rows x 8 lanes
        const float2* mlp = ML + ((size_t)(b * HW + n0 + row)) * 64 + g * 8;
        float2 v[8];
        #pragma unroll
        for (int k = 0; k < 8; k++) v[k] = mlp[k];
        float M = v[0].x;
        #pragma unroll
        for (int k = 1; k < 8; k++) M = fmaxf(M, v[k].x);
        M = fmaxf(M, __shfl_xor(M, 1));
        M = fmaxf(M, __shfl_xor(M, 2));
        M = fmaxf(M, __shfl_xor(M, 4));
        float e[8], L = 0.f;
        #pragma unroll
        for (int k = 0; k < 8; k++) { e[k] = __expf(v[k].x - M); L += v[k].y * e[k]; }
        L += __shfl_xor(L, 1);
        L += __shfl_xor(L, 2);
        L += __shfl_xor(L, 4);
        float linv = 1.f / L;
        #pragma unroll
        for (int k = 0; k < 8; k++) SclH[g * 8 + k][row] = (_Float16)(e[k] * linv);
    }

    // ---- stage chunk 0 (512 threads cover 64 rows x 64 keys) ----
    int sr = tid >> 3, sc16 = tid & 7;
    const _Float16* sp = Sg + ((size_t)(b * HW + n0 + sr)) * HW + sc16 * 8;
    {
        fp16x8 st = *(const fp16x8*)(sp);
        *(fp16x8*)&Al[0][sr][sc16 * 8] = st;
    }

    f32x4 zz = {0.f, 0.f, 0.f, 0.f};
    f32x4 acc[2][4];
    #pragma unroll
    for (int nt = 0; nt < 2; nt++)
        #pragma unroll
        for (int ct = 0; ct < 4; ct++) acc[nt][ct] = zz;

    const _Float16* hb = Hm + ((size_t)(b * C + co0 + wc + l16)) * HW;

    for (int chunk = 0; chunk < 64; chunk++) {
        int buf = chunk & 1;
        __syncthreads();
        fp16x8 st;
        if (chunk < 63) st = *(const fp16x8*)(sp + (chunk + 1) * 64);

        f32x4 tmp[2][4];
        #pragma unroll
        for (int km = 0; km < 2; km++) {
            int k = km * 32 + q * 8;
            fp16x8 afr[2], bfr[4];
            #pragma unroll
            for (int nt = 0; nt < 2; nt++)
                afr[nt] = *(const fp16x8*)&Al[buf][wn + nt * 16 + l16][k];
            #pragma unroll
            for (int ct = 0; ct < 4; ct++)
                bfr[ct] = *(const fp16x8*)(hb + (size_t)ct * 16 * HW + chunk * 64 + k);
            #pragma unroll
            for (int nt = 0; nt < 2; nt++)
                #pragma unroll
                for (int ct = 0; ct < 4; ct++)
                    tmp[nt][ct] = __builtin_amdgcn_mfma_f32_16x16x32_f16(
                        afr[nt], bfr[ct], km == 0 ? zz : tmp[nt][ct], 0, 0, 0);
        }
        // f32 scale-accumulate: acc += tmp * scale(row, tile=chunk)
        #pragma unroll
        for (int nt = 0; nt < 2; nt++) {
            fp16x4 svh = *(const fp16x4*)&SclH[chunk][wn + nt * 16 + q * 4];
            float sv[4];
            #pragma unroll
            for (int reg = 0; reg < 4; reg++) sv[reg] = (float)svh[reg];
            #pragma unroll
            for (int ct = 0; ct < 4; ct++)
                #pragma unroll
                for (int reg = 0; reg < 4; reg++)
                    acc[nt][ct][reg] += tmp[nt][ct][reg] * sv[reg];
        }
        if (chunk < 63) {
            *(fp16x8*)&Al[buf ^ 1][sr][sc16 * 8] = st;
        }
    }

    // ---- epilogue: + bo + content ----
    #pragma unroll
    for (int nt = 0; nt < 2; nt++)
        #pragma unroll
        for (int ct = 0; ct < 4; ct++) {
            int co = co0 + wc + ct * 16 + l16;
            size_t base = ((size_t)(b * C + co)) * HW + n0 + wn + nt * 16 + q * 4;
            float4 cv = *(const float4*)&xc[base];
            float bov = bo[co];
            float4 o;
            o.x = acc[nt][ct][0] + bov + cv.x;
            o.y = acc[nt][ct][1] + bov + cv.y;
            o.z = acc[nt][ct][2] + bov + cv.z;
            o.w = acc[nt][ct][3] + bov + cv.w;
            *(float4*)&out[base] = o;
        }
}

// ---------------------------------------------------------------------------
extern "C" void kernel_launch(void* const* d_in, const int* in_sizes, int n_in,
                              void* d_out, int out_size, void* d_ws, size_t ws_size,
                              hipStream_t stream)
{
    const float* content = (const float*)d_in[0];
    const float* style   = (const float*)d_in[1];
    const float* Wf = (const float*)d_in[2];
    const float* bf = (const float*)d_in[3];
    const float* Wg = (const float*)d_in[4];
    // d_in[5] = bg: provably unused (softmax row-constant)
    const float* Wh = (const float*)d_in[6];
    const float* bh = (const float*)d_in[7];
    const float* Wo = (const float*)d_in[8];
    const float* bo = (const float*)d_in[9];
    float* out = (float*)d_out;
    char* ws = (char*)d_ws;

    transpose_stats_kernel<<<4096, 256, 0, stream>>>(content, style, ws);
    finalize_stats_kernel<<<16, 256, 0, stream>>>(ws);
    precompute_kernel<<<522, 256, 0, stream>>>(Wf, Wg, Wo, Wh, bf, bh, ws);
    precompute_v_kernel<<<64, 256, 0, stream>>>(Wg, ws);
    prep_gemm_kernel<<<1024, 256, 0, stream>>>(ws);
    t_kernel<<<512, 256, 0, stream>>>(ws);
    qk_kernel<<<4096, 256, 0, stream>>>(ws);
    pv_kernel<<<512, 512, 0, stream>>>(content, bo, out, ws);
}

// Round 2
// 674.826 us; speedup vs baseline: 1.2637x; 1.2447x over previous
//
#include <hip/hip_runtime.h>

#define C 512
#define HW 4096
#define EPSV 1e-5f

typedef _Float16 fp16x8 __attribute__((ext_vector_type(8)));
typedef _Float16 fp16x4 __attribute__((ext_vector_type(4)));
typedef float f32x4 __attribute__((ext_vector_type(4)));

// ---- workspace layout (bytes) ----
#define OFF_MC    (0)
#define OFF_RC    (8192)
#define OFF_MS    (16384)
#define OFF_RS    (24576)
#define OFF_BETAF (32768)
#define OFF_V     (40960)
#define OFF_BZ    (49152)
#define OFF_T     (65536)                      // t[b][m] f32, 64 KB
#define OFF_SP    (131072)                     // stats partials float2[2][4][512][64] = 2 MB
#define OFF_A     (OFF_SP + 2097152)           // 1 MB
#define OFF_WZ    (OFF_A + 1048576)            // 1 MB
#define OFF_XCT   (OFF_WZ + 1048576)           // 16 MB
#define OFF_XST   (OFF_XCT + 16777216)         // 16 MB
#define OFF_KT    (OFF_XST + 16777216)         // 16 MB
#define OFF_HM    (OFF_KT + 16777216)          // 16 MB (fragment-tiled Hp layout)
#define OFF_ML    (OFF_HM + 16777216)          // float2[4][4096][64] = 8 MB
#define OFF_S     (OFF_ML + 8388608)           // f16 [4][4096][4096] = 128 MB
// total ~= 204 MB

// Hp tiled layout (per batch b, 2097152 f16 elements):
//   element (co, m) at ((co>>4)*512 + (m>>3))*128 + (co&15)*8 + (m&7)
// => a 64-lane wave loading B-fragments (lane = q*16+l16, 16B each) reads
//    1 KB fully contiguous: coalesced global loads in pv_kernel.

// ---------------------------------------------------------------------------
// 1) fused transpose + f16 cast + partial stats (single read of fp32 input)
// ---------------------------------------------------------------------------
__global__ void transpose_stats_kernel(const float* __restrict__ xc, const float* __restrict__ xs,
                                       char* __restrict__ ws)
{
    int bx = blockIdx.x;                  // 4096 = 2 * 4 * 8 * 64
    int tensor = bx >> 11, b = (bx >> 9) & 3, c0 = ((bx >> 6) & 7) * 64, n0 = (bx & 63) * 64;
    const float* src = tensor ? xs : xc;
    _Float16* dst = (_Float16*)(ws + (tensor ? OFF_XST : OFF_XCT));
    float2* part = (float2*)(ws + OFF_SP);

    __shared__ _Float16 tile[64][72];
    __shared__ float sred[4][64], ssred[4][64];

    int tid = threadIdx.x, cR = tid & 63, ng = tid >> 6;
    const float* p = src + ((size_t)(b * C + c0 + cR)) * HW + n0 + ng * 16;
    float s = 0.f, ss = 0.f;
    #pragma unroll
    for (int k = 0; k < 4; k++) {
        float4 v = *(const float4*)(p + k * 4);
        s += v.x + v.y + v.z + v.w;
        ss += v.x * v.x + v.y * v.y + v.z * v.z + v.w * v.w;
        int n = ng * 16 + k * 4;
        tile[n][cR] = (_Float16)v.x; tile[n + 1][cR] = (_Float16)v.y;
        tile[n + 2][cR] = (_Float16)v.z; tile[n + 3][cR] = (_Float16)v.w;
    }
    sred[ng][cR] = s; ssred[ng][cR] = ss;
    __syncthreads();
    if (tid < 64) {
        float S = sred[0][tid] + sred[1][tid] + sred[2][tid] + sred[3][tid];
        float SS = ssred[0][tid] + ssred[1][tid] + ssred[2][tid] + ssred[3][tid];
        part[((size_t)((tensor * 4 + b) * 512 + c0 + tid)) * 64 + (n0 >> 6)] = make_float2(S, SS);
    }
    #pragma unroll
    for (int i = 0; i < 2; i++) {
        int g = tid + i * 256, row = g >> 3, c8 = (g & 7) * 8;
        *(fp16x8*)&dst[((size_t)(b * HW + n0 + row)) * C + c0 + c8] = *(const fp16x8*)&tile[row][c8];
    }
}

// ---------------------------------------------------------------------------
// 1b) finalize stats
// ---------------------------------------------------------------------------
__global__ void finalize_stats_kernel(char* __restrict__ ws)
{
    int ch = blockIdx.x * 256 + threadIdx.x;       // 16 blocks -> 4096 channels
    const float2* part = (const float2*)(ws + OFF_SP) + (size_t)ch * 64;
    float S = 0.f, SS = 0.f;
    for (int k = 0; k < 64; k++) { float2 v = part[k]; S += v.x; SS += v.y; }
    int tensor = ch >> 11, rem = ch & 2047;
    float m = S / (float)HW;
    float var = (SS - S * m) / (float)(HW - 1) + EPSV;   // unbiased (n-1) + EPS
    ((float*)(ws + (tensor ? OFF_MS : OFF_MC)))[rem] = m;
    ((float*)(ws + (tensor ? OFF_RS : OFF_RC)))[rem] = rsqrtf(var);
}

// ---------------------------------------------------------------------------
// 2) small precomputes: A = Wf^T Wg, Wz = Wo Wh, betaf, bz = Wo bh
// ---------------------------------------------------------------------------
__global__ void precompute_kernel(const float* __restrict__ Wf, const float* __restrict__ Wg,
                                  const float* __restrict__ Wo, const float* __restrict__ Wh,
                                  const float* __restrict__ bf, const float* __restrict__ bh,
                                  char* __restrict__ ws)
{
    float* A = (float*)(ws + OFF_A);
    float* Wz = (float*)(ws + OFF_WZ);
    float* betaf = (float*)(ws + OFF_BETAF);
    float* bz = (float*)(ws + OFF_BZ);
    const float* mc = (const float*)(ws + OFF_MC);
    const float* rc = (const float*)(ws + OFF_RC);
    int bx = blockIdx.x, t = threadIdx.x;
    if (bx < 512) {                              // A or Wz, 2 output rows per block
        bool isA = bx < 256;
        int r0 = (isA ? bx : bx - 256) * 2;
        float a00 = 0.f, a01 = 0.f, a10 = 0.f, a11 = 0.f;
        for (int k = 0; k < C; k++) {
            float r0v, r1v, c0v, c1v;
            if (isA) {                           // A[i][j] = sum_co Wf[co][i]*Wg[co][j]
                r0v = Wf[k * C + r0]; r1v = Wf[k * C + r0 + 1];
                c0v = Wg[k * C + t];  c1v = Wg[k * C + t + 256];
            } else {                             // Wz[o][j] = sum_i Wo[o][i]*Wh[i][j]
                r0v = Wo[r0 * C + k]; r1v = Wo[(r0 + 1) * C + k];
                c0v = Wh[k * C + t];  c1v = Wh[k * C + t + 256];
            }
            a00 += r0v * c0v; a01 += r0v * c1v;
            a10 += r1v * c0v; a11 += r1v * c1v;
        }
        float* D = isA ? A : Wz;
        D[r0 * C + t] = a00;       D[r0 * C + t + 256] = a01;
        D[(r0 + 1) * C + t] = a10; D[(r0 + 1) * C + t + 256] = a11;
    } else if (bx < 520) {                       // betaf[b][co] = bf[co] - sum_i Wf[co][i]*mc*rc
        int g = (bx - 512) * 256 + t, b = g >> 9, co = g & 511;
        float acc = 0.f;
        for (int i = 0; i < C; i++) acc += Wf[co * C + i] * mc[b * C + i] * rc[b * C + i];
        betaf[g] = bf[co] - acc;
    } else {                                     // bz[co] = sum_i Wo[co][i]*bh[i]
        int co = (bx - 520) * 256 + t;
        float acc = 0.f;
        for (int i = 0; i < C; i++) acc += Wo[co * C + i] * bh[i];
        bz[co] = acc;
    }
}

// v[b][j] = rs[b][j] * sum_co betaf[b][co]*Wg[co][j]
__global__ void precompute_v_kernel(const float* __restrict__ Wg, char* __restrict__ ws)
{
    const float* betaf = (const float*)(ws + OFF_BETAF);
    const float* rs = (const float*)(ws + OFF_RS);
    float* v = (float*)(ws + OFF_V);
    int g = blockIdx.x * 32 + (threadIdx.x >> 3);   // 0..2047 output index
    int b = g >> 9, j = g & 511, cq = threadIdx.x & 7;
    float acc = 0.f;
    for (int co = cq * 64; co < cq * 64 + 64; co++) acc += betaf[b * C + co] * Wg[co * C + j];
    acc += __shfl_xor(acc, 1);
    acc += __shfl_xor(acc, 2);
    acc += __shfl_xor(acc, 4);
    if (cq == 0) v[g] = rs[b * C + j] * acc;
}

// ---------------------------------------------------------------------------
// 3) fused prep GEMM -> Kt (transposed, f16) and Hp (fragment-tiled f16)
// ---------------------------------------------------------------------------
__global__ void __launch_bounds__(256) prep_gemm_kernel(char* __restrict__ ws)
{
    const float* A = (const float*)(ws + OFF_A);
    const float* Wz = (const float*)(ws + OFF_WZ);
    const float* rc = (const float*)(ws + OFF_RC);
    const float* rs = (const float*)(ws + OFF_RS);
    const float* bz = (const float*)(ws + OFF_BZ);
    const _Float16* __restrict__ xsT = (const _Float16*)(ws + OFF_XST);
    _Float16* __restrict__ Kt = (_Float16*)(ws + OFF_KT);
    _Float16* __restrict__ Hp = (_Float16*)(ws + OFF_HM);

    int bx = blockIdx.x;                 // 1024 = 4b * 8 rowblk * 32 mblk
    int b = bx & 3, rest = bx >> 2;
    int r128 = rest >> 5, mb = rest & 31;
    int r0 = r128 * 128, m0 = mb * 128;
    int w = threadIdx.x >> 6, lane = threadIdx.x & 63, q = lane >> 4, l16 = lane & 15;
    int wr = (w & 1) * 64, wm = (w >> 1) * 64;
    bool isK = (r0 < 512);
    const float* Asrc = isK ? A : Wz;
    int rbase = (isK ? r0 : r0 - 512) + wr;

    f32x4 zz = {0.f, 0.f, 0.f, 0.f};
    f32x4 acc[4][4];
    #pragma unroll
    for (int rt = 0; rt < 4; rt++)
        #pragma unroll
        for (int mt = 0; mt < 4; mt++) acc[rt][mt] = zz;

    float rcv[4];
    #pragma unroll
    for (int rt = 0; rt < 4; rt++)
        rcv[rt] = isK ? rc[b * C + rbase + rt * 16 + l16] : 1.f;

    for (int ks = 0; ks < 16; ks++) {
        int j0 = ks * 32 + q * 8;
        float rsv[8];
        if (isK) {
            float4 u0 = *(const float4*)&rs[b * C + j0];
            float4 u1 = *(const float4*)&rs[b * C + j0 + 4];
            rsv[0] = u0.x; rsv[1] = u0.y; rsv[2] = u0.z; rsv[3] = u0.w;
            rsv[4] = u1.x; rsv[5] = u1.y; rsv[6] = u1.z; rsv[7] = u1.w;
        } else {
            #pragma unroll
            for (int jj = 0; jj < 8; jj++) rsv[jj] = 1.f;
        }
        fp16x8 afr[4];
        #pragma unroll
        for (int rt = 0; rt < 4; rt++) {
            int row = rbase + rt * 16 + l16;
            float4 a0 = *(const float4*)&Asrc[row * C + j0];
            float4 a1 = *(const float4*)&Asrc[row * C + j0 + 4];
            float av8[8];
            av8[0] = a0.x; av8[1] = a0.y; av8[2] = a0.z; av8[3] = a0.w;
            av8[4] = a1.x; av8[5] = a1.y; av8[6] = a1.z; av8[7] = a1.w;
            float sc = rcv[rt];
            #pragma unroll
            for (int jj = 0; jj < 8; jj++)
                afr[rt][jj] = (_Float16)(isK ? av8[jj] * sc * rsv[jj] : av8[jj]);
        }
        fp16x8 bfr[4];
        #pragma unroll
        for (int mt = 0; mt < 4; mt++)
            bfr[mt] = *(const fp16x8*)&xsT[((size_t)(b * HW + m0 + wm + mt * 16 + l16)) * C + j0];
        #pragma unroll
        for (int rt = 0; rt < 4; rt++)
            #pragma unroll
            for (int mt = 0; mt < 4; mt++)
                acc[rt][mt] = __builtin_amdgcn_mfma_f32_16x16x32_f16(afr[rt], bfr[mt], acc[rt][mt], 0, 0, 0);
    }

    if (isK) {
        #pragma unroll
        for (int rt = 0; rt < 4; rt++)
            #pragma unroll
            for (int mt = 0; mt < 4; mt++) {
                int m = m0 + wm + mt * 16 + l16;
                int cb = r0 + wr + rt * 16 + q * 4;
                fp16x4 h;
                h[0] = (_Float16)acc[rt][mt][0]; h[1] = (_Float16)acc[rt][mt][1];
                h[2] = (_Float16)acc[rt][mt][2]; h[3] = (_Float16)acc[rt][mt][3];
                *(fp16x4*)&Kt[((size_t)(b * HW + m)) * C + cb] = h;
            }
    } else {
        // fragment-tiled store: (co,m) -> ((co>>4)*512 + (m>>3))*128 + (co&15)*8 + (m&7)
        _Float16* HpB = Hp + (size_t)b * 2097152;
        #pragma unroll
        for (int rt = 0; rt < 4; rt++) {
            float bzv[4];
            #pragma unroll
            for (int reg = 0; reg < 4; reg++) bzv[reg] = bz[rbase + rt * 16 + q * 4 + reg];
            #pragma unroll
            for (int mt = 0; mt < 4; mt++) {
                int m = m0 + wm + mt * 16 + l16;
                int mbase = (m >> 3) * 128 + (m & 7);
                #pragma unroll
                for (int reg = 0; reg < 4; reg++) {
                    int co = rbase + rt * 16 + q * 4 + reg;
                    HpB[(size_t)(co >> 4) * 65536 + mbase + (co & 15) * 8] =
                        (_Float16)(acc[rt][mt][reg] + bzv[reg]);
                }
            }
        }
    }
}

// ---------------------------------------------------------------------------
// 4) t[b][m] = sum_j v[b][j] * xsT[b][m][j]
// ---------------------------------------------------------------------------
__global__ void t_kernel(char* __restrict__ ws)
{
    const float* v = (const float*)(ws + OFF_V);
    const _Float16* __restrict__ xsT = (const _Float16*)(ws + OFF_XST);
    float* tG = (float*)(ws + OFF_T);
    int bx = blockIdx.x;                      // 512 = 4 b * 128 mchunks(32)
    int b = bx >> 7, m0 = (bx & 127) * 32;
    int m = m0 + (threadIdx.x >> 3), cq = threadIdx.x & 7;
    const _Float16* p = xsT + ((size_t)(b * HW + m)) * C + cq * 64;
    const float* vp = v + b * C + cq * 64;
    float acc = 0.f;
    #pragma unroll
    for (int k = 0; k < 8; k++) {
        fp16x8 xv = *(const fp16x8*)(p + k * 8);
        float4 v0 = *(const float4*)(vp + k * 8);
        float4 v1 = *(const float4*)(vp + k * 8 + 4);
        acc += (float)xv[0] * v0.x + (float)xv[1] * v0.y + (float)xv[2] * v0.z + (float)xv[3] * v0.w
             + (float)xv[4] * v1.x + (float)xv[5] * v1.y + (float)xv[6] * v1.z + (float)xv[7] * v1.w;
    }
    acc += __shfl_xor(acc, 1);
    acc += __shfl_xor(acc, 2);
    acc += __shfl_xor(acc, 4);
    if (cq == 0) tG[b * HW + m] = acc;
}

// ---------------------------------------------------------------------------
// 5) pass A: S-tile = Q @ Kt^T (128x128, K=512) + t[m]; per-(row, 64-m-tile)
//    max & sumexp; stores p = exp(s - tilemax) f16 to S, (max,sum) to ML.
// ---------------------------------------------------------------------------
__global__ void __launch_bounds__(256, 4) qk_kernel(char* __restrict__ ws)
{
    const _Float16* __restrict__ xcT = (const _Float16*)(ws + OFF_XCT);
    const _Float16* __restrict__ Kt = (const _Float16*)(ws + OFF_KT);
    const float* __restrict__ tG = (const float*)(ws + OFF_T);
    float2* __restrict__ ML = (float2*)(ws + OFF_ML);
    _Float16* __restrict__ Sg = (_Float16*)(ws + OFF_S);

    int bx = blockIdx.x;                  // 4096: low3 = b*2+mhi (XCD-pinned)
    int b = (bx >> 1) & 3, mhi = bx & 1;
    int rest = bx >> 3, mlo = rest & 15, ntile = rest >> 4;
    int m0 = (mhi * 16 + mlo) * 128, n0 = ntile * 128;
    int tid = threadIdx.x, w = tid >> 6, lane = tid & 63, q = lane >> 4, l16 = lane & 15;
    int wn = (w & 1) * 64, wm = (w >> 1) * 64;

    const _Float16* ab = xcT + ((size_t)(b * HW + n0 + wn + l16)) * C;
    const _Float16* bb = Kt + ((size_t)(b * HW + m0 + wm + l16)) * C;

    f32x4 zz = {0.f, 0.f, 0.f, 0.f};
    f32x4 acc[4][4];
    #pragma unroll
    for (int nt = 0; nt < 4; nt++)
        #pragma unroll
        for (int mt = 0; mt < 4; mt++) acc[nt][mt] = zz;

    #pragma unroll 4
    for (int ks = 0; ks < 16; ks++) {
        int k = ks * 32 + q * 8;
        fp16x8 afr[4], bfr[4];
        #pragma unroll
        for (int nt = 0; nt < 4; nt++) afr[nt] = *(const fp16x8*)(ab + (size_t)nt * 16 * C + k);
        #pragma unroll
        for (int mt = 0; mt < 4; mt++) bfr[mt] = *(const fp16x8*)(bb + (size_t)mt * 16 * C + k);
        #pragma unroll
        for (int nt = 0; nt < 4; nt++)
            #pragma unroll
            for (int mt = 0; mt < 4; mt++)
                acc[nt][mt] = __builtin_amdgcn_mfma_f32_16x16x32_f16(afr[nt], bfr[mt], acc[nt][mt], 0, 0, 0);
    }

    // ---- epilogue: + t[m], per-row tile max / exp / sum ----
    float tv[4];
    #pragma unroll
    for (int mt = 0; mt < 4; mt++) tv[mt] = tG[b * HW + m0 + wm + mt * 16 + l16];
    #pragma unroll
    for (int nt = 0; nt < 4; nt++)
        #pragma unroll
        for (int mt = 0; mt < 4; mt++)
            #pragma unroll
            for (int reg = 0; reg < 4; reg++) acc[nt][mt][reg] += tv[mt];

    float rm[4][4], sum[4][4];
    #pragma unroll
    for (int nt = 0; nt < 4; nt++)
        #pragma unroll
        for (int reg = 0; reg < 4; reg++)
            rm[nt][reg] = fmaxf(fmaxf(acc[nt][0][reg], acc[nt][1][reg]),
                                fmaxf(acc[nt][2][reg], acc[nt][3][reg]));
    #pragma unroll
    for (int s = 1; s < 16; s <<= 1)
        #pragma unroll
        for (int nt = 0; nt < 4; nt++)
            #pragma unroll
            for (int reg = 0; reg < 4; reg++)
                rm[nt][reg] = fmaxf(rm[nt][reg], __shfl_xor(rm[nt][reg], s));
    #pragma unroll
    for (int nt = 0; nt < 4; nt++)
        #pragma unroll
        for (int reg = 0; reg < 4; reg++) sum[nt][reg] = 0.f;
    #pragma unroll
    for (int nt = 0; nt < 4; nt++)
        #pragma unroll
        for (int mt = 0; mt < 4; mt++)
            #pragma unroll
            for (int reg = 0; reg < 4; reg++) {
                float pv = __expf(acc[nt][mt][reg] - rm[nt][reg]);
                acc[nt][mt][reg] = pv;
                sum[nt][reg] += pv;
            }
    #pragma unroll
    for (int s = 1; s < 16; s <<= 1)
        #pragma unroll
        for (int nt = 0; nt < 4; nt++)
            #pragma unroll
            for (int reg = 0; reg < 4; reg++)
                sum[nt][reg] += __shfl_xor(sum[nt][reg], s);

    int tl = (m0 + wm) >> 6;
    if (l16 == 0) {
        #pragma unroll
        for (int nt = 0; nt < 4; nt++)
            #pragma unroll
            for (int reg = 0; reg < 4; reg++)
                ML[((size_t)(b * HW + n0 + wn + nt * 16 + q * 4 + reg)) * 64 + tl] =
                    make_float2(rm[nt][reg], sum[nt][reg]);
    }

    // ---- f16 + LDS transpose-spill, then coalesced 16B stores to S ----
    __shared__ _Float16 Pl[4][64][72];
    #pragma unroll
    for (int nt = 0; nt < 4; nt++)
        #pragma unroll
        for (int mt = 0; mt < 4; mt++)
            #pragma unroll
            for (int reg = 0; reg < 4; reg++)
                Pl[w][nt * 16 + q * 4 + reg][mt * 16 + l16] = (_Float16)acc[nt][mt][reg];
    __syncthreads();
    #pragma unroll
    for (int i = 0; i < 8; i++) {
        int row = i * 8 + (lane >> 3), c8 = (lane & 7) * 8;
        *(fp16x8*)&Sg[((size_t)(b * HW + n0 + wn + row)) * HW + m0 + wm + c8] =
            *(const fp16x8*)&Pl[w][row][c8];
    }
}

// ---------------------------------------------------------------------------
// 6) pass C: O = (p * scale) @ Hp^T ; 64-row n-tiles, 512-thread blocks.
//    Hp is fragment-tiled so B-fragment loads are 1KB-contiguous per wave;
//    loads issued right after the barrier so L2 latency overlaps the LDS
//    afr reads and the other resident block. XCD-pinned: bx&7 = cohalf*4+b.
// ---------------------------------------------------------------------------
__global__ void __launch_bounds__(512, 4) pv_kernel(const float* __restrict__ xc,
                                                    const float* __restrict__ bo,
                                                    float* __restrict__ out,
                                                    char* __restrict__ ws)
{
    const _Float16* __restrict__ Sg = (const _Float16*)(ws + OFF_S);
    const _Float16* __restrict__ Hp = (const _Float16*)(ws + OFF_HM);
    const float2* __restrict__ ML = (const float2*)(ws + OFF_ML);

    int bx = blockIdx.x;                  // 512 = 64 ntile * (cohalf*4 + b)
    int b = bx & 3, cohalf = (bx >> 2) & 1, ntile = bx >> 3;
    int n0 = ntile * 64, co0 = cohalf * 256;
    int tid = threadIdx.x, w = tid >> 6, lane = tid & 63, q = lane >> 4, l16 = lane & 15;
    int wn = (w & 1) * 32, wc = (w >> 1) * 64;

    __shared__ _Float16 SclH[64][72];         // [tile][row], f16 scales
    __shared__ _Float16 Al[2][64][72];        // S chunk, 64 keys, padded

    // ---- prologue: per-row global softmax scale (was reduce_ml) ----
    {
        int row = tid >> 3, g = tid & 7;          // 64 rows x 8 lanes
        const float2* mlp = ML + ((size_t)(b * HW + n0 + row)) * 64 + g * 8;
        float2 v[8];
        #pragma unroll
        for (int k = 0; k < 8; k++) v[k] = mlp[k];
        float M = v[0].x;
        #pragma unroll
        for (int k = 1; k < 8; k++) M = fmaxf(M, v[k].x);
        M = fmaxf(M, __shfl_xor(M, 1));
        M = fmaxf(M, __shfl_xor(M, 2));
        M = fmaxf(M, __shfl_xor(M, 4));
        float e[8], L = 0.f;
        #pragma unroll
        for (int k = 0; k < 8; k++) { e[k] = __expf(v[k].x - M); L += v[k].y * e[k]; }
        L += __shfl_xor(L, 1);
        L += __shfl_xor(L, 2);
        L += __shfl_xor(L, 4);
        float linv = 1.f / L;
        #pragma unroll
        for (int k = 0; k < 8; k++) SclH[g * 8 + k][row] = (_Float16)(e[k] * linv);
    }

    // ---- stage chunk 0 (512 threads cover 64 rows x 64 keys) ----
    int sr = tid >> 3, sc16 = tid & 7;
    const _Float16* sp = Sg + ((size_t)(b * HW + n0 + sr)) * HW + sc16 * 8;
    {
        fp16x8 st = *(const fp16x8*)(sp);
        *(fp16x8*)&Al[0][sr][sc16 * 8] = st;
    }

    f32x4 zz = {0.f, 0.f, 0.f, 0.f};
    f32x4 acc[2][4];
    #pragma unroll
    for (int nt = 0; nt < 2; nt++)
        #pragma unroll
        for (int ct = 0; ct < 4; ct++) acc[nt][ct] = zz;

    // fragment-tiled Hp base: q and l16 folded in; per (ct): +ct*65536,
    // per (chunk,km): +(chunk*8+km*4)*128. Lane addresses are linear*16B.
    const _Float16* hb = Hp + (size_t)b * 2097152
                            + (size_t)((co0 + wc) >> 4) * 65536
                            + (size_t)q * 128 + (size_t)l16 * 8;

    for (int chunk = 0; chunk < 64; chunk++) {
        int buf = chunk & 1;
        __syncthreads();
        fp16x8 st;
        if (chunk < 63) st = *(const fp16x8*)(sp + (chunk + 1) * 64);

        // issue all 8 Hm loads first (coalesced, independent of LDS)
        fp16x8 bfr[2][4];
        #pragma unroll
        for (int km = 0; km < 2; km++)
            #pragma unroll
            for (int ct = 0; ct < 4; ct++)
                bfr[km][ct] = *(const fp16x8*)(hb + (size_t)ct * 65536 + (chunk * 8 + km * 4) * 128);

        f32x4 tmp[2][4];
        #pragma unroll
        for (int km = 0; km < 2; km++) {
            int k = km * 32 + q * 8;
            fp16x8 afr[2];
            #pragma unroll
            for (int nt = 0; nt < 2; nt++)
                afr[nt] = *(const fp16x8*)&Al[buf][wn + nt * 16 + l16][k];
            #pragma unroll
            for (int nt = 0; nt < 2; nt++)
                #pragma unroll
                for (int ct = 0; ct < 4; ct++)
                    tmp[nt][ct] = __builtin_amdgcn_mfma_f32_16x16x32_f16(
                        afr[nt], bfr[km][ct], km == 0 ? zz : tmp[nt][ct], 0, 0, 0);
        }
        // f32 scale-accumulate: acc += tmp * scale(row, tile=chunk)
        #pragma unroll
        for (int nt = 0; nt < 2; nt++) {
            fp16x4 svh = *(const fp16x4*)&SclH[chunk][wn + nt * 16 + q * 4];
            float sv[4];
            #pragma unroll
            for (int reg = 0; reg < 4; reg++) sv[reg] = (float)svh[reg];
            #pragma unroll
            for (int ct = 0; ct < 4; ct++)
                #pragma unroll
                for (int reg = 0; reg < 4; reg++)
                    acc[nt][ct][reg] += tmp[nt][ct][reg] * sv[reg];
        }
        if (chunk < 63) {
            *(fp16x8*)&Al[buf ^ 1][sr][sc16 * 8] = st;
        }
    }

    // ---- epilogue: + bo + content ----
    #pragma unroll
    for (int nt = 0; nt < 2; nt++)
        #pragma unroll
        for (int ct = 0; ct < 4; ct++) {
            int co = co0 + wc + ct * 16 + l16;
            size_t base = ((size_t)(b * C + co)) * HW + n0 + wn + nt * 16 + q * 4;
            float4 cv = *(const float4*)&xc[base];
            float bov = bo[co];
            float4 o;
            o.x = acc[nt][ct][0] + bov + cv.x;
            o.y = acc[nt][ct][1] + bov + cv.y;
            o.z = acc[nt][ct][2] + bov + cv.z;
            o.w = acc[nt][ct][3] + bov + cv.w;
            *(float4*)&out[base] = o;
        }
}

// ---------------------------------------------------------------------------
extern "C" void kernel_launch(void* const* d_in, const int* in_sizes, int n_in,
                              void* d_out, int out_size, void* d_ws, size_t ws_size,
                              hipStream_t stream)
{
    const float* content = (const float*)d_in[0];
    const float* style   = (const float*)d_in[1];
    const float* Wf = (const float*)d_in[2];
    const float* bf = (const float*)d_in[3];
    const float* Wg = (const float*)d_in[4];
    // d_in[5] = bg: provably unused (softmax row-constant)
    const float* Wh = (const float*)d_in[6];
    const float* bh = (const float*)d_in[7];
    const float* Wo = (const float*)d_in[8];
    const float* bo = (const float*)d_in[9];
    float* out = (float*)d_out;
    char* ws = (char*)d_ws;

    transpose_stats_kernel<<<4096, 256, 0, stream>>>(content, style, ws);
    finalize_stats_kernel<<<16, 256, 0, stream>>>(ws);
    precompute_kernel<<<522, 256, 0, stream>>>(Wf, Wg, Wo, Wh, bf, bh, ws);
    precompute_v_kernel<<<64, 256, 0, stream>>>(Wg, ws);
    prep_gemm_kernel<<<1024, 256, 0, stream>>>(ws);
    t_kernel<<<512, 256, 0, stream>>>(ws);
    qk_kernel<<<4096, 256, 0, stream>>>(ws);
    pv_kernel<<<512, 512, 0, stream>>>(content, bo, out, ws);
}

// Round 3
// 512.305 us; speedup vs baseline: 1.6645x; 1.3172x over previous
//
#include <hip/hip_runtime.h>

#define C 512
#define HW 4096
#define EPSV 1e-5f

typedef _Float16 fp16x8 __attribute__((ext_vector_type(8)));
typedef _Float16 fp16x4 __attribute__((ext_vector_type(4)));
typedef float f32x4 __attribute__((ext_vector_type(4)));

// ---- workspace layout (bytes) ----
#define OFF_MC    (0)
#define OFF_RC    (8192)
#define OFF_MS    (16384)
#define OFF_RS    (24576)
#define OFF_BETAF (32768)
#define OFF_V     (40960)
#define OFF_BZ    (49152)
#define OFF_T     (65536)                      // t[b][m] f32, 64 KB
#define OFF_SP    (131072)                     // stats partials float2[2][4][512][64] = 2 MB
#define OFF_A     (OFF_SP + 2097152)           // 1 MB
#define OFF_WZ    (OFF_A + 1048576)            // 1 MB
#define OFF_XCT   (OFF_WZ + 1048576)           // 16 MB (fragment-tiled)
#define OFF_XST   (OFF_XCT + 16777216)         // 16 MB (fragment-tiled)
#define OFF_KT    (OFF_XST + 16777216)         // 16 MB (fragment-tiled)
#define OFF_HM    (OFF_KT + 16777216)          // 16 MB (fragment-tiled Hp layout)
#define OFF_ML    (OFF_HM + 16777216)          // float2[4][4096][64] = 8 MB
#define OFF_S     (OFF_ML + 8388608)           // f16 [4][4096][4096] = 128 MB
// total ~= 204 MB

// Fragment-tiled layout for transposed f16 tensors (xcT, xsT, Kt), per batch:
//   elem (row n, col c) -> ((n>>4)*16 + (c>>5))*512 + ((c>>3)&3)*128 + (n&15)*8 + (c&7)
// Pure bit-permutation (bijective). An MFMA fragment load (lane = q*16+l16,
// 8 f16 per lane) reads 1 KB fully contiguous -> perfectly coalesced.
#define FT_IDX(n, c) ((((size_t)((n) >> 4) * 16 + ((c) >> 5)) * 512) + \
                      ((((c) >> 3) & 3) * 128) + (((n) & 15) * 8) + ((c) & 7))

// Hp tiled layout (per batch b, 2097152 f16 elements):
//   element (co, m) at ((co>>4)*512 + (m>>3))*128 + (co&15)*8 + (m&7)

// ---------------------------------------------------------------------------
// 1) fused transpose + f16 cast + partial stats (single read of fp32 input)
// ---------------------------------------------------------------------------
__global__ void transpose_stats_kernel(const float* __restrict__ xc, const float* __restrict__ xs,
                                       char* __restrict__ ws)
{
    int bx = blockIdx.x;                  // 4096 = 2 * 4 * 8 * 64
    int tensor = bx >> 11, b = (bx >> 9) & 3, c0 = ((bx >> 6) & 7) * 64, n0 = (bx & 63) * 64;
    const float* src = tensor ? xs : xc;
    _Float16* dst = (_Float16*)(ws + (tensor ? OFF_XST : OFF_XCT));
    float2* part = (float2*)(ws + OFF_SP);

    __shared__ _Float16 tile[64][72];
    __shared__ float sred[4][64], ssred[4][64];

    int tid = threadIdx.x, cR = tid & 63, ng = tid >> 6;
    const float* p = src + ((size_t)(b * C + c0 + cR)) * HW + n0 + ng * 16;
    float s = 0.f, ss = 0.f;
    #pragma unroll
    for (int k = 0; k < 4; k++) {
        float4 v = *(const float4*)(p + k * 4);
        s += v.x + v.y + v.z + v.w;
        ss += v.x * v.x + v.y * v.y + v.z * v.z + v.w * v.w;
        int n = ng * 16 + k * 4;
        tile[n][cR] = (_Float16)v.x; tile[n + 1][cR] = (_Float16)v.y;
        tile[n + 2][cR] = (_Float16)v.z; tile[n + 3][cR] = (_Float16)v.w;
    }
    sred[ng][cR] = s; ssred[ng][cR] = ss;
    __syncthreads();
    if (tid < 64) {
        float S = sred[0][tid] + sred[1][tid] + sred[2][tid] + sred[3][tid];
        float SS = ssred[0][tid] + ssred[1][tid] + ssred[2][tid] + ssred[3][tid];
        part[((size_t)((tensor * 4 + b) * 512 + c0 + tid)) * 64 + (n0 >> 6)] = make_float2(S, SS);
    }
    _Float16* dstB = dst + (size_t)b * HW * C;
    #pragma unroll
    for (int i = 0; i < 2; i++) {
        int g = tid + i * 256, row = g >> 3, c8 = (g & 7) * 8;
        int n = n0 + row, c = c0 + c8;
        *(fp16x8*)&dstB[FT_IDX(n, c)] = *(const fp16x8*)&tile[row][c8];
    }
}

// ---------------------------------------------------------------------------
// 1b) finalize stats
// ---------------------------------------------------------------------------
__global__ void finalize_stats_kernel(char* __restrict__ ws)
{
    int ch = blockIdx.x * 256 + threadIdx.x;       // 16 blocks -> 4096 channels
    const float2* part = (const float2*)(ws + OFF_SP) + (size_t)ch * 64;
    float S = 0.f, SS = 0.f;
    for (int k = 0; k < 64; k++) { float2 v = part[k]; S += v.x; SS += v.y; }
    int tensor = ch >> 11, rem = ch & 2047;
    float m = S / (float)HW;
    float var = (SS - S * m) / (float)(HW - 1) + EPSV;   // unbiased (n-1) + EPS
    ((float*)(ws + (tensor ? OFF_MS : OFF_MC)))[rem] = m;
    ((float*)(ws + (tensor ? OFF_RS : OFF_RC)))[rem] = rsqrtf(var);
}

// ---------------------------------------------------------------------------
// 2) small precomputes: A = Wf^T Wg, Wz = Wo Wh, betaf, bz = Wo bh
// ---------------------------------------------------------------------------
__global__ void precompute_kernel(const float* __restrict__ Wf, const float* __restrict__ Wg,
                                  const float* __restrict__ Wo, const float* __restrict__ Wh,
                                  const float* __restrict__ bf, const float* __restrict__ bh,
                                  char* __restrict__ ws)
{
    float* A = (float*)(ws + OFF_A);
    float* Wz = (float*)(ws + OFF_WZ);
    float* betaf = (float*)(ws + OFF_BETAF);
    float* bz = (float*)(ws + OFF_BZ);
    const float* mc = (const float*)(ws + OFF_MC);
    const float* rc = (const float*)(ws + OFF_RC);
    int bx = blockIdx.x, t = threadIdx.x;
    if (bx < 512) {                              // A or Wz, 2 output rows per block
        bool isA = bx < 256;
        int r0 = (isA ? bx : bx - 256) * 2;
        float a00 = 0.f, a01 = 0.f, a10 = 0.f, a11 = 0.f;
        for (int k = 0; k < C; k++) {
            float r0v, r1v, c0v, c1v;
            if (isA) {                           // A[i][j] = sum_co Wf[co][i]*Wg[co][j]
                r0v = Wf[k * C + r0]; r1v = Wf[k * C + r0 + 1];
                c0v = Wg[k * C + t];  c1v = Wg[k * C + t + 256];
            } else {                             // Wz[o][j] = sum_i Wo[o][i]*Wh[i][j]
                r0v = Wo[r0 * C + k]; r1v = Wo[(r0 + 1) * C + k];
                c0v = Wh[k * C + t];  c1v = Wh[k * C + t + 256];
            }
            a00 += r0v * c0v; a01 += r0v * c1v;
            a10 += r1v * c0v; a11 += r1v * c1v;
        }
        float* D = isA ? A : Wz;
        D[r0 * C + t] = a00;       D[r0 * C + t + 256] = a01;
        D[(r0 + 1) * C + t] = a10; D[(r0 + 1) * C + t + 256] = a11;
    } else if (bx < 520) {                       // betaf[b][co] = bf[co] - sum_i Wf[co][i]*mc*rc
        int g = (bx - 512) * 256 + t, b = g >> 9, co = g & 511;
        float acc = 0.f;
        for (int i = 0; i < C; i++) acc += Wf[co * C + i] * mc[b * C + i] * rc[b * C + i];
        betaf[g] = bf[co] - acc;
    } else {                                     // bz[co] = sum_i Wo[co][i]*bh[i]
        int co = (bx - 520) * 256 + t;
        float acc = 0.f;
        for (int i = 0; i < C; i++) acc += Wo[co * C + i] * bh[i];
        bz[co] = acc;
    }
}

// v[b][j] = rs[b][j] * sum_co betaf[b][co]*Wg[co][j]
__global__ void precompute_v_kernel(const float* __restrict__ Wg, char* __restrict__ ws)
{
    const float* betaf = (const float*)(ws + OFF_BETAF);
    const float* rs = (const float*)(ws + OFF_RS);
    float* v = (float*)(ws + OFF_V);
    int g = blockIdx.x * 32 + (threadIdx.x >> 3);   // 0..2047 output index
    int b = g >> 9, j = g & 511, cq = threadIdx.x & 7;
    float acc = 0.f;
    for (int co = cq * 64; co < cq * 64 + 64; co++) acc += betaf[b * C + co] * Wg[co * C + j];
    acc += __shfl_xor(acc, 1);
    acc += __shfl_xor(acc, 2);
    acc += __shfl_xor(acc, 4);
    if (cq == 0) v[g] = rs[b * C + j] * acc;
}

// ---------------------------------------------------------------------------
// 3) fused prep GEMM -> Kt (fragment-tiled f16) and Hp (fragment-tiled f16)
// ---------------------------------------------------------------------------
__global__ void __launch_bounds__(256) prep_gemm_kernel(char* __restrict__ ws)
{
    const float* A = (const float*)(ws + OFF_A);
    const float* Wz = (const float*)(ws + OFF_WZ);
    const float* rc = (const float*)(ws + OFF_RC);
    const float* rs = (const float*)(ws + OFF_RS);
    const float* bz = (const float*)(ws + OFF_BZ);
    const _Float16* __restrict__ xsT = (const _Float16*)(ws + OFF_XST);
    _Float16* __restrict__ Kt = (_Float16*)(ws + OFF_KT);
    _Float16* __restrict__ Hp = (_Float16*)(ws + OFF_HM);

    int bx = blockIdx.x;                 // 1024 = 4b * 8 rowblk * 32 mblk
    int b = bx & 3, rest = bx >> 2;
    int r128 = rest >> 5, mb = rest & 31;
    int r0 = r128 * 128, m0 = mb * 128;
    int w = threadIdx.x >> 6, lane = threadIdx.x & 63, q = lane >> 4, l16 = lane & 15;
    int wr = (w & 1) * 64, wm = (w >> 1) * 64;
    bool isK = (r0 < 512);
    const float* Asrc = isK ? A : Wz;
    int rbase = (isK ? r0 : r0 - 512) + wr;

    f32x4 zz = {0.f, 0.f, 0.f, 0.f};
    f32x4 acc[4][4];
    #pragma unroll
    for (int rt = 0; rt < 4; rt++)
        #pragma unroll
        for (int mt = 0; mt < 4; mt++) acc[rt][mt] = zz;

    float rcv[4];
    #pragma unroll
    for (int rt = 0; rt < 4; rt++)
        rcv[rt] = isK ? rc[b * C + rbase + rt * 16 + l16] : 1.f;

    // fragment-tiled xsT base: lane offset q*128 + l16*8 folded in
    const _Float16* xb = xsT + (size_t)b * HW * C
                             + (size_t)((m0 + wm) >> 4) * 8192 + q * 128 + l16 * 8;

    for (int ks = 0; ks < 16; ks++) {
        int j0 = ks * 32 + q * 8;
        float rsv[8];
        if (isK) {
            float4 u0 = *(const float4*)&rs[b * C + j0];
            float4 u1 = *(const float4*)&rs[b * C + j0 + 4];
            rsv[0] = u0.x; rsv[1] = u0.y; rsv[2] = u0.z; rsv[3] = u0.w;
            rsv[4] = u1.x; rsv[5] = u1.y; rsv[6] = u1.z; rsv[7] = u1.w;
        } else {
            #pragma unroll
            for (int jj = 0; jj < 8; jj++) rsv[jj] = 1.f;
        }
        fp16x8 afr[4];
        #pragma unroll
        for (int rt = 0; rt < 4; rt++) {
            int row = rbase + rt * 16 + l16;
            float4 a0 = *(const float4*)&Asrc[row * C + j0];
            float4 a1 = *(const float4*)&Asrc[row * C + j0 + 4];
            float av8[8];
            av8[0] = a0.x; av8[1] = a0.y; av8[2] = a0.z; av8[3] = a0.w;
            av8[4] = a1.x; av8[5] = a1.y; av8[6] = a1.z; av8[7] = a1.w;
            float sc = rcv[rt];
            #pragma unroll
            for (int jj = 0; jj < 8; jj++)
                afr[rt][jj] = (_Float16)(isK ? av8[jj] * sc * rsv[jj] : av8[jj]);
        }
        fp16x8 bfr[4];
        #pragma unroll
        for (int mt = 0; mt < 4; mt++)
            bfr[mt] = *(const fp16x8*)(xb + (size_t)(mt * 16 + ks) * 512);
        #pragma unroll
        for (int rt = 0; rt < 4; rt++)
            #pragma unroll
            for (int mt = 0; mt < 4; mt++)
                acc[rt][mt] = __builtin_amdgcn_mfma_f32_16x16x32_f16(afr[rt], bfr[mt], acc[rt][mt], 0, 0, 0);
    }

    if (isK) {
        _Float16* KtB = Kt + (size_t)b * HW * C;
        #pragma unroll
        for (int rt = 0; rt < 4; rt++)
            #pragma unroll
            for (int mt = 0; mt < 4; mt++) {
                int m = m0 + wm + mt * 16 + l16;
                int cb = r0 + wr + rt * 16 + q * 4;
                fp16x4 h;
                h[0] = (_Float16)acc[rt][mt][0]; h[1] = (_Float16)acc[rt][mt][1];
                h[2] = (_Float16)acc[rt][mt][2]; h[3] = (_Float16)acc[rt][mt][3];
                *(fp16x4*)&KtB[FT_IDX(m, cb)] = h;
            }
    } else {
        // fragment-tiled store: (co,m) -> ((co>>4)*512 + (m>>3))*128 + (co&15)*8 + (m&7)
        _Float16* HpB = Hp + (size_t)b * 2097152;
        #pragma unroll
        for (int rt = 0; rt < 4; rt++) {
            float bzv[4];
            #pragma unroll
            for (int reg = 0; reg < 4; reg++) bzv[reg] = bz[rbase + rt * 16 + q * 4 + reg];
            #pragma unroll
            for (int mt = 0; mt < 4; mt++) {
                int m = m0 + wm + mt * 16 + l16;
                int mbase = (m >> 3) * 128 + (m & 7);
                #pragma unroll
                for (int reg = 0; reg < 4; reg++) {
                    int co = rbase + rt * 16 + q * 4 + reg;
                    HpB[(size_t)(co >> 4) * 65536 + mbase + (co & 15) * 8] =
                        (_Float16)(acc[rt][mt][reg] + bzv[reg]);
                }
            }
        }
    }
}

// ---------------------------------------------------------------------------
// 4) t[b][m] = sum_j v[b][j] * xsT[b][m][j]   (fragment-tiled xsT)
// ---------------------------------------------------------------------------
__global__ void t_kernel(char* __restrict__ ws)
{
    const float* v = (const float*)(ws + OFF_V);
    const _Float16* __restrict__ xsT = (const _Float16*)(ws + OFF_XST);
    float* tG = (float*)(ws + OFF_T);
    int bx = blockIdx.x;                      // 512 = 4 b * 128 mchunks(32)
    int b = bx >> 7, m0 = (bx & 127) * 32;
    int m = m0 + (threadIdx.x >> 3), cq = threadIdx.x & 7;
    const _Float16* p = xsT + (size_t)b * HW * C + (size_t)(m >> 4) * 8192 + (m & 15) * 8;
    const float* vp = v + b * C + cq * 64;
    float acc = 0.f;
    #pragma unroll
    for (int k = 0; k < 8; k++) {
        // col = cq*64 + k*8 -> subtile (cq*2 + (k>>2)), q = k&3
        fp16x8 xv = *(const fp16x8*)(p + (cq * 2 + (k >> 2)) * 512 + (k & 3) * 128);
        float4 v0 = *(const float4*)(vp + k * 8);
        float4 v1 = *(const float4*)(vp + k * 8 + 4);
        acc += (float)xv[0] * v0.x + (float)xv[1] * v0.y + (float)xv[2] * v0.z + (float)xv[3] * v0.w
             + (float)xv[4] * v1.x + (float)xv[5] * v1.y + (float)xv[6] * v1.z + (float)xv[7] * v1.w;
    }
    acc += __shfl_xor(acc, 1);
    acc += __shfl_xor(acc, 2);
    acc += __shfl_xor(acc, 4);
    if (cq == 0) tG[b * HW + m] = acc;
}

// ---------------------------------------------------------------------------
// 5) pass A: S-tile = Q @ Kt^T (128x128, K=512) + t[m]; per-(row, 64-m-tile)
//    max & sumexp; stores p = exp(s - tilemax) f16 to S, (max,sum) to ML.
//    xcT/Kt fragment-tiled: every A/B fragment load is 1KB wave-linear.
// ---------------------------------------------------------------------------
__global__ void __launch_bounds__(256, 4) qk_kernel(char* __restrict__ ws)
{
    const _Float16* __restrict__ xcT = (const _Float16*)(ws + OFF_XCT);
    const _Float16* __restrict__ Kt = (const _Float16*)(ws + OFF_KT);
    const float* __restrict__ tG = (const float*)(ws + OFF_T);
    float2* __restrict__ ML = (float2*)(ws + OFF_ML);
    _Float16* __restrict__ Sg = (_Float16*)(ws + OFF_S);

    int bx = blockIdx.x;                  // 4096: low3 = b*2+mhi (XCD-pinned)
    int b = (bx >> 1) & 3, mhi = bx & 1;
    int rest = bx >> 3, mlo = rest & 15, ntile = rest >> 4;
    int m0 = (mhi * 16 + mlo) * 128, n0 = ntile * 128;
    int tid = threadIdx.x, w = tid >> 6, lane = tid & 63, q = lane >> 4, l16 = lane & 15;
    int wn = (w & 1) * 64, wm = (w >> 1) * 64;

    const _Float16* ab = xcT + (size_t)b * HW * C
                             + (size_t)((n0 + wn) >> 4) * 8192 + q * 128 + l16 * 8;
    const _Float16* bb = Kt + (size_t)b * HW * C
                            + (size_t)((m0 + wm) >> 4) * 8192 + q * 128 + l16 * 8;

    f32x4 zz = {0.f, 0.f, 0.f, 0.f};
    f32x4 acc[4][4];
    #pragma unroll
    for (int nt = 0; nt < 4; nt++)
        #pragma unroll
        for (int mt = 0; mt < 4; mt++) acc[nt][mt] = zz;

    #pragma unroll 4
    for (int ks = 0; ks < 16; ks++) {
        fp16x8 afr[4], bfr[4];
        #pragma unroll
        for (int nt = 0; nt < 4; nt++)
            afr[nt] = *(const fp16x8*)(ab + (size_t)(nt * 16 + ks) * 512);
        #pragma unroll
        for (int mt = 0; mt < 4; mt++)
            bfr[mt] = *(const fp16x8*)(bb + (size_t)(mt * 16 + ks) * 512);
        #pragma unroll
        for (int nt = 0; nt < 4; nt++)
            #pragma unroll
            for (int mt = 0; mt < 4; mt++)
                acc[nt][mt] = __builtin_amdgcn_mfma_f32_16x16x32_f16(afr[nt], bfr[mt], acc[nt][mt], 0, 0, 0);
    }

    // ---- epilogue: + t[m], per-row tile max / exp / sum ----
    float tv[4];
    #pragma unroll
    for (int mt = 0; mt < 4; mt++) tv[mt] = tG[b * HW + m0 + wm + mt * 16 + l16];
    #pragma unroll
    for (int nt = 0; nt < 4; nt++)
        #pragma unroll
        for (int mt = 0; mt < 4; mt++)
            #pragma unroll
            for (int reg = 0; reg < 4; reg++) acc[nt][mt][reg] += tv[mt];

    float rm[4][4], sum[4][4];
    #pragma unroll
    for (int nt = 0; nt < 4; nt++)
        #pragma unroll
        for (int reg = 0; reg < 4; reg++)
            rm[nt][reg] = fmaxf(fmaxf(acc[nt][0][reg], acc[nt][1][reg]),
                                fmaxf(acc[nt][2][reg], acc[nt][3][reg]));
    #pragma unroll
    for (int s = 1; s < 16; s <<= 1)
        #pragma unroll
        for (int nt = 0; nt < 4; nt++)
            #pragma unroll
            for (int reg = 0; reg < 4; reg++)
                rm[nt][reg] = fmaxf(rm[nt][reg], __shfl_xor(rm[nt][reg], s));
    #pragma unroll
    for (int nt = 0; nt < 4; nt++)
        #pragma unroll
        for (int reg = 0; reg < 4; reg++) sum[nt][reg] = 0.f;
    #pragma unroll
    for (int nt = 0; nt < 4; nt++)
        #pragma unroll
        for (int mt = 0; mt < 4; mt++)
            #pragma unroll
            for (int reg = 0; reg < 4; reg++) {
                float pv = __expf(acc[nt][mt][reg] - rm[nt][reg]);
                acc[nt][mt][reg] = pv;
                sum[nt][reg] += pv;
            }
    #pragma unroll
    for (int s = 1; s < 16; s <<= 1)
        #pragma unroll
        for (int nt = 0; nt < 4; nt++)
            #pragma unroll
            for (int reg = 0; reg < 4; reg++)
                sum[nt][reg] += __shfl_xor(sum[nt][reg], s);

    int tl = (m0 + wm) >> 6;
    if (l16 == 0) {
        #pragma unroll
        for (int nt = 0; nt < 4; nt++)
            #pragma unroll
            for (int reg = 0; reg < 4; reg++)
                ML[((size_t)(b * HW + n0 + wn + nt * 16 + q * 4 + reg)) * 64 + tl] =
                    make_float2(rm[nt][reg], sum[nt][reg]);
    }

    // ---- f16 + LDS transpose-spill, then coalesced 16B stores to S ----
    __shared__ _Float16 Pl[4][64][72];
    #pragma unroll
    for (int nt = 0; nt < 4; nt++)
        #pragma unroll
        for (int mt = 0; mt < 4; mt++)
            #pragma unroll
            for (int reg = 0; reg < 4; reg++)
                Pl[w][nt * 16 + q * 4 + reg][mt * 16 + l16] = (_Float16)acc[nt][mt][reg];
    __syncthreads();
    #pragma unroll
    for (int i = 0; i < 8; i++) {
        int row = i * 8 + (lane >> 3), c8 = (lane & 7) * 8;
        *(fp16x8*)&Sg[((size_t)(b * HW + n0 + wn + row)) * HW + m0 + wm + c8] =
            *(const fp16x8*)&Pl[w][row][c8];
    }
}

// ---------------------------------------------------------------------------
// 6) pass C: O = (p * scale) @ Hp^T ; 64-row n-tiles, 512-thread blocks.
//    Hp fragment-tiled: B-fragment loads are 1KB-contiguous per wave.
//    XCD-pinned: bx&7 = cohalf*4+b.
// ---------------------------------------------------------------------------
__global__ void __launch_bounds__(512, 4) pv_kernel(const float* __restrict__ xc,
                                                    const float* __restrict__ bo,
                                                    float* __restrict__ out,
                                                    char* __restrict__ ws)
{
    const _Float16* __restrict__ Sg = (const _Float16*)(ws + OFF_S);
    const _Float16* __restrict__ Hp = (const _Float16*)(ws + OFF_HM);
    const float2* __restrict__ ML = (const float2*)(ws + OFF_ML);

    int bx = blockIdx.x;                  // 512 = 64 ntile * (cohalf*4 + b)
    int b = bx & 3, cohalf = (bx >> 2) & 1, ntile = bx >> 3;
    int n0 = ntile * 64, co0 = cohalf * 256;
    int tid = threadIdx.x, w = tid >> 6, lane = tid & 63, q = lane >> 4, l16 = lane & 15;
    int wn = (w & 1) * 32, wc = (w >> 1) * 64;

    __shared__ _Float16 SclH[64][72];         // [tile][row], f16 scales
    __shared__ _Float16 Al[2][64][72];        // S chunk, 64 keys, padded

    // ---- prologue: per-row global softmax scale (was reduce_ml) ----
    {
        int row = tid >> 3, g = tid & 7;          // 64 rows x 8 lanes
        const float2* mlp = ML + ((size_t)(b * HW + n0 + row)) * 64 + g * 8;
        float2 v[8];
        #pragma unroll
        for (int k = 0; k < 8; k++) v[k] = mlp[k];
        float M = v[0].x;
        #pragma unroll
        for (int k = 1; k < 8; k++) M = fmaxf(M, v[k].x);
        M = fmaxf(M, __shfl_xor(M, 1));
        M = fmaxf(M, __shfl_xor(M, 2));
        M = fmaxf(M, __shfl_xor(M, 4));
        float e[8], L = 0.f;
        #pragma unroll
        for (int k = 0; k < 8; k++) { e[k] = __expf(v[k].x - M); L += v[k].y * e[k]; }
        L += __shfl_xor(L, 1);
        L += __shfl_xor(L, 2);
        L += __shfl_xor(L, 4);
        float linv = 1.f / L;
        #pragma unroll
        for (int k = 0; k < 8; k++) SclH[g * 8 + k][row] = (_Float16)(e[k] * linv);
    }

    // ---- stage chunk 0 (512 threads cover 64 rows x 64 keys) ----
    int sr = tid >> 3, sc16 = tid & 7;
    const _Float16* sp = Sg + ((size_t)(b * HW + n0 + sr)) * HW + sc16 * 8;
    {
        fp16x8 st = *(const fp16x8*)(sp);
        *(fp16x8*)&Al[0][sr][sc16 * 8] = st;
    }

    f32x4 zz = {0.f, 0.f, 0.f, 0.f};
    f32x4 acc[2][4];
    #pragma unroll
    for (int nt = 0; nt < 2; nt++)
        #pragma unroll
        for (int ct = 0; ct < 4; ct++) acc[nt][ct] = zz;

    // fragment-tiled Hp base: q and l16 folded in; per (ct): +ct*65536,
    // per (chunk,km): +(chunk*8+km*4)*128. Lane addresses are linear*16B.
    const _Float16* hb = Hp + (size_t)b * 2097152
                            + (size_t)((co0 + wc) >> 4) * 65536
                            + (size_t)q * 128 + (size_t)l16 * 8;

    for (int chunk = 0; chunk < 64; chunk++) {
        int buf = chunk & 1;
        __syncthreads();
        fp16x8 st;
        if (chunk < 63) st = *(const fp16x8*)(sp + (chunk + 1) * 64);

        // issue all 8 Hm loads first (coalesced, independent of LDS)
        fp16x8 bfr[2][4];
        #pragma unroll
        for (int km = 0; km < 2; km++)
            #pragma unroll
            for (int ct = 0; ct < 4; ct++)
                bfr[km][ct] = *(const fp16x8*)(hb + (size_t)ct * 65536 + (chunk * 8 + km * 4) * 128);

        f32x4 tmp[2][4];
        #pragma unroll
        for (int km = 0; km < 2; km++) {
            int k = km * 32 + q * 8;
            fp16x8 afr[2];
            #pragma unroll
            for (int nt = 0; nt < 2; nt++)
                afr[nt] = *(const fp16x8*)&Al[buf][wn + nt * 16 + l16][k];
            #pragma unroll
            for (int nt = 0; nt < 2; nt++)
                #pragma unroll
                for (int ct = 0; ct < 4; ct++)
                    tmp[nt][ct] = __builtin_amdgcn_mfma_f32_16x16x32_f16(
                        afr[nt], bfr[km][ct], km == 0 ? zz : tmp[nt][ct], 0, 0, 0);
        }
        // f32 scale-accumulate: acc += tmp * scale(row, tile=chunk)
        #pragma unroll
        for (int nt = 0; nt < 2; nt++) {
            fp16x4 svh = *(const fp16x4*)&SclH[chunk][wn + nt * 16 + q * 4];
            float sv[4];
            #pragma unroll
            for (int reg = 0; reg < 4; reg++) sv[reg] = (float)svh[reg];
            #pragma unroll
            for (int ct = 0; ct < 4; ct++)
                #pragma unroll
                for (int reg = 0; reg < 4; reg++)
                    acc[nt][ct][reg] += tmp[nt][ct][reg] * sv[reg];
        }
        if (chunk < 63) {
            *(fp16x8*)&Al[buf ^ 1][sr][sc16 * 8] = st;
        }
    }

    // ---- epilogue: + bo + content ----
    #pragma unroll
    for (int nt = 0; nt < 2; nt++)
        #pragma unroll
        for (int ct = 0; ct < 4; ct++) {
            int co = co0 + wc + ct * 16 + l16;
            size_t base = ((size_t)(b * C + co)) * HW + n0 + wn + nt * 16 + q * 4;
            float4 cv = *(const float4*)&xc[base];
            float bov = bo[co];
            float4 o;
            o.x = acc[nt][ct][0] + bov + cv.x;
            o.y = acc[nt][ct][1] + bov + cv.y;
            o.z = acc[nt][ct][2] + bov + cv.z;
            o.w = acc[nt][ct][3] + bov + cv.w;
            *(float4*)&out[base] = o;
        }
}

// ---------------------------------------------------------------------------
extern "C" void kernel_launch(void* const* d_in, const int* in_sizes, int n_in,
                              void* d_out, int out_size, void* d_ws, size_t ws_size,
                              hipStream_t stream)
{
    const float* content = (const float*)d_in[0];
    const float* style   = (const float*)d_in[1];
    const float* Wf = (const float*)d_in[2];
    const float* bf = (const float*)d_in[3];
    const float* Wg = (const float*)d_in[4];
    // d_in[5] = bg: provably unused (softmax row-constant)
    const float* Wh = (const float*)d_in[6];
    const float* bh = (const float*)d_in[7];
    const float* Wo = (const float*)d_in[8];
    const float* bo = (const float*)d_in[9];
    float* out = (float*)d_out;
    char* ws = (char*)d_ws;

    transpose_stats_kernel<<<4096, 256, 0, stream>>>(content, style, ws);
    finalize_stats_kernel<<<16, 256, 0, stream>>>(ws);
    precompute_kernel<<<522, 256, 0, stream>>>(Wf, Wg, Wo, Wh, bf, bh, ws);
    precompute_v_kernel<<<64, 256, 0, stream>>>(Wg, ws);
    prep_gemm_kernel<<<1024, 256, 0, stream>>>(ws);
    t_kernel<<<512, 256, 0, stream>>>(ws);
    qk_kernel<<<4096, 256, 0, stream>>>(ws);
    pv_kernel<<<512, 512, 0, stream>>>(content, bo, out, ws);
}